// Round 9
// baseline (101.260 us; speedup 1.0000x reference)
//
#include <hip/hip_runtime.h>
#include <math.h>

#define GDIM 640
#define NDIM 320
#define NB 8
#define NM 200000
#define PI_F 3.14159265358979323846f

// binning geometry
#define TILE 32
#define TPB  20                   // tiles per batch per axis
#define TT   (TPB * TPB)          // 400 tiles per batch
#define NTILES (NB * TT)          // 3200
#define CAP  704                  // bucket capacity (mean 500, corner max 531, +7.5 sigma)
#define STW  35                   // staged patch width: global rows x0-1 .. x0+33
#define CURSTRIDE 16              // pad cursor counters to one 64B line each

// scatter geometry
#define SBD  512                  // scatter block threads
#define SPT  8                    // samples per thread
#define CHUNK (SBD * SPT)         // 4096 samples per block
#define SBLK_PER_B ((NM + CHUNK - 1) / CHUNK)   // 49

// ---------- Bessel I0 (Abramowitz & Stegun 9.8.1/9.8.2, |err| < 2e-7) ----------
__device__ __forceinline__ float bessel_i0f(float x) {
    if (x < 3.75f) {
        float t = x * (1.0f / 3.75f);
        t *= t;
        return 1.0f + t * (3.5156229f + t * (3.0899424f + t * (1.2067492f +
                     t * (0.2659732f + t * (0.0360768f + t * 0.0045813f)))));
    }
    float t = 3.75f / x;
    float p = 0.39894228f + t * (0.01328592f + t * (0.00225319f + t * (-0.00157565f +
              t * (0.00916281f + t * (-0.02057706f + t * (0.02635537f +
              t * (-0.01647633f + t * 0.00392377f)))))));
    return p * __expf(x) * rsqrtf(x);
}

// ---------- deapodization 1/c helper ----------
__device__ __forceinline__ float deapod_c(int i, float beta2) {
    float xs = (float)(i - NDIM / 2) * (1.0f / (float)GDIM);
    float p = PI_F * 3.0f * xs;
    float arg = beta2 - p * p;
    float s = sqrtf(fabsf(arg));
    if (arg > 0.0f) return sinhf(s) / s;
    return (s < 1e-12f) ? 1.0f : sinf(s) / s;   // not reached for these params
}

// ---------- Kaiser-Bessel kernel weight ----------
__device__ __forceinline__ float kbw(float d, float beta) {
    if (fabsf(d) > 1.5f) return 0.0f;
    float u = d * (2.0f / 3.0f);
    float t = 1.0f - u * u;
    t = fmaxf(t, 0.0f);
    return bessel_i0f(beta * sqrtf(t));
}

__device__ __forceinline__ float2 cmul(float2 a, float2 b) {
    return make_float2(a.x * b.x - a.y * b.y, a.x * b.y + a.y * b.x);
}

// ---------- 640-point FFT, in-wave shuffle version ----------
__device__ __forceinline__ void fft640_wave(float2* lds, int tid) {
    const int f = tid >> 6;         // wave id = k1
    const int L = tid & 63;
    float sw, cw;

    __sincosf(-2.0f * PI_F * (float)f * 0.2f, &sw, &cw);
    const float2 w5 = make_float2(cw, sw);
    float2 A = make_float2(0.0f, 0.0f), B = make_float2(0.0f, 0.0f);
    float2 wa = make_float2(1.0f, 0.0f);
#pragma unroll
    for (int a = 0; a < 5; ++a) {
        float2 xa = lds[a * 128 + L];
        float2 xb = lds[a * 128 + L + 64];
        A.x += xa.x * wa.x - xa.y * wa.y;  A.y += xa.x * wa.y + xa.y * wa.x;
        B.x += xb.x * wa.x - xb.y * wa.y;  B.y += xb.x * wa.y + xb.y * wa.x;
        wa = cmul(wa, w5);
    }
    __sincosf(-2.0f * PI_F * (float)(L * f) * (1.0f / 640.0f), &sw, &cw);
    A = cmul(A, make_float2(cw, sw));
    __sincosf(-2.0f * PI_F * (float)((L + 64) * f) * (1.0f / 640.0f), &sw, &cw);
    B = cmul(B, make_float2(cw, sw));

    {
        float2 s = make_float2(A.x + B.x, A.y + B.y);
        float2 d = make_float2(A.x - B.x, A.y - B.y);
        __sincosf(-PI_F * (float)L * (1.0f / 64.0f), &sw, &cw);
        B = cmul(d, make_float2(cw, sw));
        A = s;
    }
#pragma unroll
    for (int h = 32; h >= 1; h >>= 1) {
        const int jj = L & (h - 1);
        __sincosf(-PI_F * (float)jj * (1.0f / (float)h), &sw, &cw);
        const float2 w = make_float2(cw, sw);
        float2 Ao, Bo;
        Ao.x = __shfl_xor(A.x, h, 64); Ao.y = __shfl_xor(A.y, h, 64);
        Bo.x = __shfl_xor(B.x, h, 64); Bo.y = __shfl_xor(B.y, h, 64);
        if ((L & h) == 0) {
            A = make_float2(A.x + Ao.x, A.y + Ao.y);
            B = make_float2(B.x + Bo.x, B.y + Bo.y);
        } else {
            A = cmul(make_float2(Ao.x - A.x, Ao.y - A.y), w);
            B = cmul(make_float2(Bo.x - B.x, Bo.y - B.y), w);
        }
    }

    __syncthreads();

    const int e = (int)(__brev((unsigned)L) >> 26);
    const int ka = f + 10 * e;
    const int kb = ka + 5;
    const int ksa = (ka >= 320) ? (ka - 320) : (ka + 320);
    const int ksb = (kb >= 320) ? (kb - 320) : (kb + 320);
    lds[ksa] = A;
    lds[ksb] = B;
    __syncthreads();
}

// ---------- cursor zero (replaces 40us hipMemsetAsync fill dispatch) ----------
__global__ __launch_bounds__(512) void zero_cursor(unsigned int* __restrict__ cursor) {
    const int i = blockIdx.x * 512 + threadIdx.x;
    if (i < NTILES * CURSTRIDE) cursor[i] = 0u;
}

// ---------- Pass A: deapod + pad + ifftshift + FFT over x (non-zero rows only) ----------
__global__ __launch_bounds__(320) void pass_a(const float* __restrict__ x_re,
                                              const float* __restrict__ x_im,
                                              float2* __restrict__ buf1c,
                                              float beta2) {
    __shared__ float2 lds[640];
    const int b = blockIdx.y;
    const int r = blockIdx.x;          // compact row 0..319
    const int tid = threadIdx.x;

    const int ry = (r < 160) ? (r + 160) : (r - 160);   // source image row 0..319
    const float cy = deapod_c(ry, beta2);
    const float scale = 1.0f / (cy * (float)GDIM);

    for (int i = tid; i < GDIM; i += 320) {
        int xx = (i >= 320) ? (i - 320) : (i + 320);
        float2 v = make_float2(0.0f, 0.0f);
        if (xx >= 160 && xx < 480) {
            int rx = xx - 160;
            float cx = deapod_c(rx, beta2);
            float sc = scale / cx;
            size_t off = ((size_t)b * NDIM + ry) * NDIM + rx;
            v.x = x_re[off] * sc;
            v.y = x_im[off] * sc;
        }
        lds[i] = v;
    }
    __syncthreads();

    fft640_wave(lds, tid);

    float2* dst = buf1c + ((size_t)b * NDIM + r) * GDIM;
    for (int i = tid; i < GDIM; i += 320) dst[i] = lds[i];
}

// ---------- Pass B: FFT over y, 4 columns per block, compact kbuf[b][kx][ky] ----------
__global__ __launch_bounds__(320) void pass_b(const float2* __restrict__ buf1c,
                                              float2* __restrict__ kbuf) {
    __shared__ float2 colsT[4][648];   // stride 648 to spread banks
    const int b = blockIdx.y;
    const int kxs0 = blockIdx.x * 4;
    const int tid = threadIdx.x;

    for (int base = 0; base < NDIM; base += 80) {
        int r = base + (tid >> 2);
        int c = tid & 3;
        float2 v = buf1c[((size_t)b * NDIM + r) * GDIM + kxs0 + c];
        int y = (r < 160) ? r : (r + 320);       // compact -> ifftshifted y
        colsT[c][y] = v;
    }
    for (int i = tid; i < 1280; i += 320) {
        colsT[i & 3][160 + (i >> 2)] = make_float2(0.0f, 0.0f);
    }
    __syncthreads();

#pragma unroll
    for (int c = 0; c < 4; ++c) {
        fft640_wave(&colsT[c][0], tid);
    }

#pragma unroll
    for (int c = 0; c < 4; ++c) {
        float2* dst = kbuf + ((size_t)b * GDIM + (kxs0 + c)) * GDIM;
        for (int i = tid; i < GDIM; i += 320) dst[i] = colsT[c][i];
    }
}

// ---------- Scatter: LDS-aggregated two-phase binning ----------
__global__ __launch_bounds__(SBD) void scatter_kernel(const float* __restrict__ traj,
                                                      const float* __restrict__ dcf,
                                                      unsigned int* __restrict__ cursor,
                                                      float4* __restrict__ recs) {
    __shared__ unsigned int lcount[TT];
    __shared__ unsigned int lbase[TT];
    const int bid = blockIdx.x;
    const int b = bid & 7;
    const int chunk = bid >> 3;
    const int m0 = chunk * CHUNK + (int)threadIdx.x * SPT;

    for (int i = threadIdx.x; i < TT; i += SBD) lcount[i] = 0;
    __syncthreads();

    float cx[SPT], cy[SPT], sd[SPT];
    unsigned int packed[SPT];        // (t << 13) | local_offset
    int nv = 0;

    if (m0 < NM) {
        nv = NM - m0; if (nv > SPT) nv = SPT;
        const float* tr_x = traj + ((size_t)b * 2 + 0) * NM;
        const float* tr_y = traj + ((size_t)b * 2 + 1) * NM;
        const float* dc   = dcf + (size_t)b * NM;
        if (nv == SPT) {   // aligned fast path (m0 % 8 == 0)
#pragma unroll
            for (int g = 0; g < SPT / 4; ++g) {
                const float4 xv = *(const float4*)(tr_x + m0 + 4 * g);
                const float4 yv = *(const float4*)(tr_y + m0 + 4 * g);
                const float4 dv = *(const float4*)(dc + m0 + 4 * g);
                cx[4*g+0] = xv.x; cx[4*g+1] = xv.y; cx[4*g+2] = xv.z; cx[4*g+3] = xv.w;
                cy[4*g+0] = yv.x; cy[4*g+1] = yv.y; cy[4*g+2] = yv.z; cy[4*g+3] = yv.w;
                sd[4*g+0] = dv.x; sd[4*g+1] = dv.y; sd[4*g+2] = dv.z; sd[4*g+3] = dv.w;
            }
        } else {
            for (int s = 0; s < nv; ++s) {
                cx[s] = tr_x[m0 + s]; cy[s] = tr_y[m0 + s]; sd[s] = dc[m0 + s];
            }
        }
        for (int s = 0; s < nv; ++s) {
            cx[s] = (cx[s] + 0.5f) * (float)GDIM;
            cy[s] = (cy[s] + 0.5f) * (float)GDIM;
            sd[s] = sqrtf(sd[s]);
            const int px = (int)floorf(cx[s] - 1.0f) + 1;
            const int py = (int)floorf(cy[s] - 1.0f) + 1;
            const int tX = min(px >> 5, TPB - 1);
            const int tY = min(py >> 5, TPB - 1);
            const unsigned int t = (unsigned int)(tX * TPB + tY);
            const unsigned int loc = atomicAdd(&lcount[t], 1u);
            packed[s] = (t << 13) | loc;       // loc < 4096 < 2^13
        }
    }
    __syncthreads();

    for (int i = threadIdx.x; i < TT; i += SBD) {
        unsigned int c = lcount[i];
        lbase[i] = c ? atomicAdd(&cursor[((size_t)b * TT + i) * CURSTRIDE], c) : 0u;
    }
    __syncthreads();

    for (int s = 0; s < nv; ++s) {
        const unsigned int t = packed[s] >> 13;
        const unsigned int pos = lbase[t] + (packed[s] & 0x1FFFu);
        if (pos < CAP) {
            recs[((size_t)b * TT + t) * CAP + pos] =
                make_float4(cx[s], cy[s], sd[s], __int_as_float(m0 + s));
        }
    }
}

// ---------- Binned gather: one block per tile, kbuf patch staged in LDS ----------
__global__ __launch_bounds__(256) void binned_gather(const unsigned int* __restrict__ cursor,
                                                     const float4* __restrict__ recs,
                                                     const float2* __restrict__ kbuf,
                                                     float2* __restrict__ out,
                                                     float beta) {
    __shared__ float2 tilebuf[STW * STW];
    const int t = blockIdx.x;
    const int b = t / TT;
    const int rr2 = t - b * TT;
    const int x0 = (rr2 / TPB) * TILE;
    const int y0 = (rr2 % TPB) * TILE;
    const int tid = threadIdx.x;

    // stage 35x35 patch starting at (x0-1, y0-1), wrap-aware both directions
    const float2* kbb = kbuf + (size_t)b * GDIM * GDIM;
    for (int i = tid; i < STW * STW; i += 256) {
        int r = i / STW;
        int c = i - r * STW;
        int gr = x0 + r - 1;
        if (gr < 0) gr += GDIM; else if (gr >= GDIM) gr -= GDIM;
        int gc = y0 + c - 1;
        if (gc < 0) gc += GDIM; else if (gc >= GDIM) gc -= GDIM;
        tilebuf[i] = kbb[(size_t)gr * GDIM + gc];
    }
    __syncthreads();

    unsigned int cnt = cursor[(size_t)t * CURSTRIDE];
    if (cnt > CAP) cnt = CAP;

    for (unsigned int s = tid; s < cnt; s += 256) {
        const float4 rec = recs[(size_t)t * CAP + s];
        const float cx = rec.x, cy = rec.y, sd = rec.z;
        const int m = __float_as_int(rec.w);

        const int bxi = (int)floorf(cx - 1.0f);
        const int byi = (int)floorf(cy - 1.0f);
        const float fx = cx - (float)bxi;       // [1,2)
        const float fy = cy - (float)byi;
        const int lx = (bxi + 1) - x0;          // 0..31
        const int ly = (byi + 1) - y0;

        float wx[3], wy[3];
#pragma unroll
        for (int l = 0; l < 3; ++l) {
            wx[l] = kbw(fx - (float)l, beta);
            wy[l] = kbw(fy - (float)l, beta);
        }

        float accx = 0.0f, accy = 0.0f;
#pragma unroll
        for (int i = 0; i < 3; ++i) {
            const float2* row = &tilebuf[(lx + i) * STW + ly];
            const float w0 = wx[i] * wy[0];
            const float w1 = wx[i] * wy[1];
            const float w2 = wx[i] * wy[2];
            float2 v0 = row[0], v1 = row[1], v2 = row[2];
            accx += v0.x * w0 + v1.x * w1 + v2.x * w2;
            accy += v0.y * w0 + v1.y * w1 + v2.y * w2;
        }
        out[(size_t)b * NM + m] = make_float2(accx * sd, accy * sd);
    }
}

extern "C" void kernel_launch(void* const* d_in, const int* in_sizes, int n_in,
                              void* d_out, int out_size, void* d_ws, size_t ws_size,
                              hipStream_t stream) {
    const float* x_re = (const float*)d_in[0];
    const float* x_im = (const float*)d_in[1];
    const float* traj = (const float*)d_in[2];
    const float* dcf  = (const float*)d_in[3];

    char* ws = (char*)d_ws;
    float2* buf1c = (float2*)ws;                                   // 13.1 MB
    ws += (size_t)NB * NDIM * GDIM * sizeof(float2);
    float2* kbuf = (float2*)ws;                                    // 26.2 MB
    ws += (size_t)NB * GDIM * GDIM * sizeof(float2);
    unsigned int* cursor = (unsigned int*)ws;                      // 204.8 KB (64B-padded)
    ws += (size_t)NTILES * CURSTRIDE * sizeof(unsigned int);
    float4* recs = (float4*)ws;                                    // 36.0 MB

    const double beta_d = M_PI * sqrt((1.5 * 1.5) * (1.5 * 1.5) - 0.8);
    const float beta = (float)beta_d;
    const float beta2 = (float)(beta_d * beta_d);

    zero_cursor<<<(NTILES * CURSTRIDE + 511) / 512, 512, 0, stream>>>(cursor);

    dim3 gridA(NDIM, NB);
    pass_a<<<gridA, 320, 0, stream>>>(x_re, x_im, buf1c, beta2);

    dim3 gridB(GDIM / 4, NB);
    pass_b<<<gridB, 320, 0, stream>>>(buf1c, kbuf);

    scatter_kernel<<<SBLK_PER_B * NB, SBD, 0, stream>>>(traj, dcf, cursor, recs);

    binned_gather<<<NTILES, 256, 0, stream>>>(cursor, recs, kbuf,
                                              (float2*)d_out, beta);
}

// Round 10
// 89.133 us; speedup vs baseline: 1.1361x; 1.1361x over previous
//
#include <hip/hip_runtime.h>
#include <math.h>

#define GDIM 640
#define NDIM 320
#define NB 8
#define NM 200000
#define PI_F 3.14159265358979323846f

// binning geometry
#define TILE 32
#define TPB  20                   // tiles per batch per axis
#define TT   (TPB * TPB)          // 400 tiles per batch
#define NTILES (NB * TT)          // 3200
#define CAP  704                  // bucket capacity (mean 500, corner max 531, +7.5 sigma)
#define STW  35                   // staged patch width: global rows x0-1 .. x0+33
#define CURSTRIDE 16              // pad cursor counters to one 64B line each
#define CURWORDS (NTILES * CURSTRIDE)   // 51200

// scatter geometry
#define SBD  512                  // scatter block threads
#define SPT  8                    // samples per thread
#define CHUNK (SBD * SPT)         // 4096 samples per block
#define SBLK_PER_B ((NM + CHUNK - 1) / CHUNK)   // 49

// ---------- Bessel I0 (Abramowitz & Stegun 9.8.1/9.8.2, |err| < 2e-7) ----------
__device__ __forceinline__ float bessel_i0f(float x) {
    if (x < 3.75f) {
        float t = x * (1.0f / 3.75f);
        t *= t;
        return 1.0f + t * (3.5156229f + t * (3.0899424f + t * (1.2067492f +
                     t * (0.2659732f + t * (0.0360768f + t * 0.0045813f)))));
    }
    float t = 3.75f / x;
    float p = 0.39894228f + t * (0.01328592f + t * (0.00225319f + t * (-0.00157565f +
              t * (0.00916281f + t * (-0.02057706f + t * (0.02635537f +
              t * (-0.01647633f + t * 0.00392377f)))))));
    return p * __expf(x) * rsqrtf(x);
}

// ---------- deapodization 1/c helper ----------
__device__ __forceinline__ float deapod_c(int i, float beta2) {
    float xs = (float)(i - NDIM / 2) * (1.0f / (float)GDIM);
    float p = PI_F * 3.0f * xs;
    float arg = beta2 - p * p;
    float s = sqrtf(fabsf(arg));
    if (arg > 0.0f) return sinhf(s) / s;
    return (s < 1e-12f) ? 1.0f : sinf(s) / s;   // not reached for these params
}

// ---------- Kaiser-Bessel kernel weight ----------
__device__ __forceinline__ float kbw(float d, float beta) {
    if (fabsf(d) > 1.5f) return 0.0f;
    float u = d * (2.0f / 3.0f);
    float t = 1.0f - u * u;
    t = fmaxf(t, 0.0f);
    return bessel_i0f(beta * sqrtf(t));
}

__device__ __forceinline__ float2 cmul(float2 a, float2 b) {
    return make_float2(a.x * b.x - a.y * b.y, a.x * b.y + a.y * b.x);
}

// ---------- 640-point FFT, in-wave shuffle version ----------
__device__ __forceinline__ void fft640_wave(float2* lds, int tid) {
    const int f = tid >> 6;         // wave id = k1
    const int L = tid & 63;
    float sw, cw;

    __sincosf(-2.0f * PI_F * (float)f * 0.2f, &sw, &cw);
    const float2 w5 = make_float2(cw, sw);
    float2 A = make_float2(0.0f, 0.0f), B = make_float2(0.0f, 0.0f);
    float2 wa = make_float2(1.0f, 0.0f);
#pragma unroll
    for (int a = 0; a < 5; ++a) {
        float2 xa = lds[a * 128 + L];
        float2 xb = lds[a * 128 + L + 64];
        A.x += xa.x * wa.x - xa.y * wa.y;  A.y += xa.x * wa.y + xa.y * wa.x;
        B.x += xb.x * wa.x - xb.y * wa.y;  B.y += xb.x * wa.y + xb.y * wa.x;
        wa = cmul(wa, w5);
    }
    __sincosf(-2.0f * PI_F * (float)(L * f) * (1.0f / 640.0f), &sw, &cw);
    A = cmul(A, make_float2(cw, sw));
    __sincosf(-2.0f * PI_F * (float)((L + 64) * f) * (1.0f / 640.0f), &sw, &cw);
    B = cmul(B, make_float2(cw, sw));

    {
        float2 s = make_float2(A.x + B.x, A.y + B.y);
        float2 d = make_float2(A.x - B.x, A.y - B.y);
        __sincosf(-PI_F * (float)L * (1.0f / 64.0f), &sw, &cw);
        B = cmul(d, make_float2(cw, sw));
        A = s;
    }
#pragma unroll
    for (int h = 32; h >= 1; h >>= 1) {
        const int jj = L & (h - 1);
        __sincosf(-PI_F * (float)jj * (1.0f / (float)h), &sw, &cw);
        const float2 w = make_float2(cw, sw);
        float2 Ao, Bo;
        Ao.x = __shfl_xor(A.x, h, 64); Ao.y = __shfl_xor(A.y, h, 64);
        Bo.x = __shfl_xor(B.x, h, 64); Bo.y = __shfl_xor(B.y, h, 64);
        if ((L & h) == 0) {
            A = make_float2(A.x + Ao.x, A.y + Ao.y);
            B = make_float2(B.x + Bo.x, B.y + Bo.y);
        } else {
            A = cmul(make_float2(Ao.x - A.x, Ao.y - A.y), w);
            B = cmul(make_float2(Bo.x - B.x, Bo.y - B.y), w);
        }
    }

    __syncthreads();

    const int e = (int)(__brev((unsigned)L) >> 26);
    const int ka = f + 10 * e;
    const int kb = ka + 5;
    const int ksa = (ka >= 320) ? (ka - 320) : (ka + 320);
    const int ksb = (kb >= 320) ? (kb - 320) : (kb + 320);
    lds[ksa] = A;
    lds[ksb] = B;
    __syncthreads();
}

// ---------- Pass A: deapod + pad + ifftshift + FFT over x (non-zero rows only) ----------
// Also zeroes the scatter cursor array (folded dispatch; visible to scatter
// via the pass_a->pass_b->scatter kernel-boundary ordering).
__global__ __launch_bounds__(320) void pass_a(const float* __restrict__ x_re,
                                              const float* __restrict__ x_im,
                                              float2* __restrict__ buf1c,
                                              unsigned int* __restrict__ cursor,
                                              float beta2) {
    __shared__ float2 lds[640];
    const int b = blockIdx.y;
    const int r = blockIdx.x;          // compact row 0..319
    const int tid = threadIdx.x;

    if (b == 0 && r < CURWORDS / 320) {
        cursor[r * 320 + tid] = 0u;    // 160 blocks x 320 = 51200 words
    }

    const int ry = (r < 160) ? (r + 160) : (r - 160);   // source image row 0..319
    const float cy = deapod_c(ry, beta2);
    const float scale = 1.0f / (cy * (float)GDIM);

    for (int i = tid; i < GDIM; i += 320) {
        int xx = (i >= 320) ? (i - 320) : (i + 320);
        float2 v = make_float2(0.0f, 0.0f);
        if (xx >= 160 && xx < 480) {
            int rx = xx - 160;
            float cx = deapod_c(rx, beta2);
            float sc = scale / cx;
            size_t off = ((size_t)b * NDIM + ry) * NDIM + rx;
            v.x = x_re[off] * sc;
            v.y = x_im[off] * sc;
        }
        lds[i] = v;
    }
    __syncthreads();

    fft640_wave(lds, tid);

    float2* dst = buf1c + ((size_t)b * NDIM + r) * GDIM;
    for (int i = tid; i < GDIM; i += 320) dst[i] = lds[i];
}

// ---------- Pass B: FFT over y, 4 columns per block, compact kbuf[b][kx][ky] ----------
__global__ __launch_bounds__(320) void pass_b(const float2* __restrict__ buf1c,
                                              float2* __restrict__ kbuf) {
    __shared__ float2 colsT[4][648];   // stride 648 to spread banks
    const int b = blockIdx.y;
    const int kxs0 = blockIdx.x * 4;
    const int tid = threadIdx.x;

    for (int base = 0; base < NDIM; base += 80) {
        int r = base + (tid >> 2);
        int c = tid & 3;
        float2 v = buf1c[((size_t)b * NDIM + r) * GDIM + kxs0 + c];
        int y = (r < 160) ? r : (r + 320);       // compact -> ifftshifted y
        colsT[c][y] = v;
    }
    for (int i = tid; i < 1280; i += 320) {
        colsT[i & 3][160 + (i >> 2)] = make_float2(0.0f, 0.0f);
    }
    __syncthreads();

#pragma unroll
    for (int c = 0; c < 4; ++c) {
        fft640_wave(&colsT[c][0], tid);
    }

#pragma unroll
    for (int c = 0; c < 4; ++c) {
        float2* dst = kbuf + ((size_t)b * GDIM + (kxs0 + c)) * GDIM;
        for (int i = tid; i < GDIM; i += 320) dst[i] = colsT[c][i];
    }
}

// ---------- Scatter: LDS-aggregated two-phase binning ----------
__global__ __launch_bounds__(SBD) void scatter_kernel(const float* __restrict__ traj,
                                                      const float* __restrict__ dcf,
                                                      unsigned int* __restrict__ cursor,
                                                      float4* __restrict__ recs) {
    __shared__ unsigned int lcount[TT];
    __shared__ unsigned int lbase[TT];
    const int bid = blockIdx.x;
    const int b = bid & 7;
    const int chunk = bid >> 3;
    const int m0 = chunk * CHUNK + (int)threadIdx.x * SPT;

    for (int i = threadIdx.x; i < TT; i += SBD) lcount[i] = 0;
    __syncthreads();

    float cx[SPT], cy[SPT], sd[SPT];
    unsigned int packed[SPT];        // (t << 13) | local_offset
    int nv = 0;

    if (m0 < NM) {
        nv = NM - m0; if (nv > SPT) nv = SPT;
        const float* tr_x = traj + ((size_t)b * 2 + 0) * NM;
        const float* tr_y = traj + ((size_t)b * 2 + 1) * NM;
        const float* dc   = dcf + (size_t)b * NM;
        if (nv == SPT) {   // aligned fast path (m0 % 8 == 0)
#pragma unroll
            for (int g = 0; g < SPT / 4; ++g) {
                const float4 xv = *(const float4*)(tr_x + m0 + 4 * g);
                const float4 yv = *(const float4*)(tr_y + m0 + 4 * g);
                const float4 dv = *(const float4*)(dc + m0 + 4 * g);
                cx[4*g+0] = xv.x; cx[4*g+1] = xv.y; cx[4*g+2] = xv.z; cx[4*g+3] = xv.w;
                cy[4*g+0] = yv.x; cy[4*g+1] = yv.y; cy[4*g+2] = yv.z; cy[4*g+3] = yv.w;
                sd[4*g+0] = dv.x; sd[4*g+1] = dv.y; sd[4*g+2] = dv.z; sd[4*g+3] = dv.w;
            }
        } else {
            for (int s = 0; s < nv; ++s) {
                cx[s] = tr_x[m0 + s]; cy[s] = tr_y[m0 + s]; sd[s] = dc[m0 + s];
            }
        }
        for (int s = 0; s < nv; ++s) {
            cx[s] = (cx[s] + 0.5f) * (float)GDIM;
            cy[s] = (cy[s] + 0.5f) * (float)GDIM;
            sd[s] = sqrtf(sd[s]);
            const int px = (int)floorf(cx[s] - 1.0f) + 1;
            const int py = (int)floorf(cy[s] - 1.0f) + 1;
            const int tX = min(px >> 5, TPB - 1);
            const int tY = min(py >> 5, TPB - 1);
            const unsigned int t = (unsigned int)(tX * TPB + tY);
            const unsigned int loc = atomicAdd(&lcount[t], 1u);
            packed[s] = (t << 13) | loc;       // loc < 4096 < 2^13
        }
    }
    __syncthreads();

    for (int i = threadIdx.x; i < TT; i += SBD) {
        unsigned int c = lcount[i];
        lbase[i] = c ? atomicAdd(&cursor[((size_t)b * TT + i) * CURSTRIDE], c) : 0u;
    }
    __syncthreads();

    for (int s = 0; s < nv; ++s) {
        const unsigned int t = packed[s] >> 13;
        const unsigned int pos = lbase[t] + (packed[s] & 0x1FFFu);
        if (pos < CAP) {
            recs[((size_t)b * TT + t) * CAP + pos] =
                make_float4(cx[s], cy[s], sd[s], __int_as_float(m0 + s));
        }
    }
}

// ---------- Binned gather: one block per tile, XCD-localized per batch ----------
// b = bid & 7 so (with round-robin block->XCD dispatch) XCD k serves only
// batch k: its out slice (1.6 MB), kbuf slice (3.3 MB) and recs slice stay
// resident in that XCD's 4 MB L2 -> scattered 8B writes coalesce in L2.
__global__ __launch_bounds__(256) void binned_gather(const unsigned int* __restrict__ cursor,
                                                     const float4* __restrict__ recs,
                                                     const float2* __restrict__ kbuf,
                                                     float2* __restrict__ out,
                                                     float beta) {
    __shared__ float2 tilebuf[STW * STW];
    const int bid = blockIdx.x;
    const int b = bid & 7;
    const int tile = bid >> 3;               // 0..399
    const int t = b * TT + tile;
    const int x0 = (tile / TPB) * TILE;
    const int y0 = (tile % TPB) * TILE;
    const int tid = threadIdx.x;

    // stage 35x35 patch starting at (x0-1, y0-1), wrap-aware both directions
    const float2* kbb = kbuf + (size_t)b * GDIM * GDIM;
    for (int i = tid; i < STW * STW; i += 256) {
        int r = i / STW;
        int c = i - r * STW;
        int gr = x0 + r - 1;
        if (gr < 0) gr += GDIM; else if (gr >= GDIM) gr -= GDIM;
        int gc = y0 + c - 1;
        if (gc < 0) gc += GDIM; else if (gc >= GDIM) gc -= GDIM;
        tilebuf[i] = kbb[(size_t)gr * GDIM + gc];
    }
    __syncthreads();

    unsigned int cnt = cursor[(size_t)t * CURSTRIDE];
    if (cnt > CAP) cnt = CAP;

    for (unsigned int s = tid; s < cnt; s += 256) {
        const float4 rec = recs[(size_t)t * CAP + s];
        const float cx = rec.x, cy = rec.y, sd = rec.z;
        const int m = __float_as_int(rec.w);

        const int bxi = (int)floorf(cx - 1.0f);
        const int byi = (int)floorf(cy - 1.0f);
        const float fx = cx - (float)bxi;       // [1,2)
        const float fy = cy - (float)byi;
        const int lx = (bxi + 1) - x0;          // 0..31
        const int ly = (byi + 1) - y0;

        float wx[3], wy[3];
#pragma unroll
        for (int l = 0; l < 3; ++l) {
            wx[l] = kbw(fx - (float)l, beta);
            wy[l] = kbw(fy - (float)l, beta);
        }

        float accx = 0.0f, accy = 0.0f;
#pragma unroll
        for (int i = 0; i < 3; ++i) {
            const float2* row = &tilebuf[(lx + i) * STW + ly];
            const float w0 = wx[i] * wy[0];
            const float w1 = wx[i] * wy[1];
            const float w2 = wx[i] * wy[2];
            float2 v0 = row[0], v1 = row[1], v2 = row[2];
            accx += v0.x * w0 + v1.x * w1 + v2.x * w2;
            accy += v0.y * w0 + v1.y * w1 + v2.y * w2;
        }
        out[(size_t)b * NM + m] = make_float2(accx * sd, accy * sd);
    }
}

extern "C" void kernel_launch(void* const* d_in, const int* in_sizes, int n_in,
                              void* d_out, int out_size, void* d_ws, size_t ws_size,
                              hipStream_t stream) {
    const float* x_re = (const float*)d_in[0];
    const float* x_im = (const float*)d_in[1];
    const float* traj = (const float*)d_in[2];
    const float* dcf  = (const float*)d_in[3];

    char* ws = (char*)d_ws;
    float2* buf1c = (float2*)ws;                                   // 13.1 MB
    ws += (size_t)NB * NDIM * GDIM * sizeof(float2);
    float2* kbuf = (float2*)ws;                                    // 26.2 MB
    ws += (size_t)NB * GDIM * GDIM * sizeof(float2);
    unsigned int* cursor = (unsigned int*)ws;                      // 204.8 KB (64B-padded)
    ws += (size_t)CURWORDS * sizeof(unsigned int);
    float4* recs = (float4*)ws;                                    // 36.0 MB

    const double beta_d = M_PI * sqrt((1.5 * 1.5) * (1.5 * 1.5) - 0.8);
    const float beta = (float)beta_d;
    const float beta2 = (float)(beta_d * beta_d);

    dim3 gridA(NDIM, NB);
    pass_a<<<gridA, 320, 0, stream>>>(x_re, x_im, buf1c, cursor, beta2);

    dim3 gridB(GDIM / 4, NB);
    pass_b<<<gridB, 320, 0, stream>>>(buf1c, kbuf);

    scatter_kernel<<<SBLK_PER_B * NB, SBD, 0, stream>>>(traj, dcf, cursor, recs);

    binned_gather<<<NTILES, 256, 0, stream>>>(cursor, recs, kbuf,
                                              (float2*)d_out, beta);
}